// Round 16
// baseline (77.380 us; speedup 1.0000x reference)
//
#include <hip/hip_runtime.h>

// GraphConv: out = d ∘ (A @ ((d∘X) @ W^T)) + b,  d = rsqrt(clip(rowsum(A),1e-6))
// B=4, N=2048, F=128. All f32 I/O, size-based binding (R6-verified).
// R12/13/14 all ~52-56 µs: barriered LDS-staged k3 hits the m97-structure
// ceiling (vmcnt(0) drain at every __syncthreads voids prefetch). R15: k3 is
// wave-private, ZERO barriers, ZERO LDS — each wave owns 16n x 32o, loads
// clean short8 fragments straight from global (A pre-converted to bf16 by k1,
// Zt L2-resident). Fragment conventions identical to R10-verified kernels.
// Fallback (ws too small): R12 path verbatim.

#define NN 2048
#define FF 128
#define WS_BASE  (32768u + 4u * 128u * 2048u * 2u)            // dinv + Zt = 2129920
#define WS_FULL  (WS_BASE + 4u * 2048u * 2048u * 2u)          // + Abf16 = 35.7 MB

typedef __attribute__((ext_vector_type(4))) float f32x4;
typedef __attribute__((ext_vector_type(8))) short short8;

// f32 -> bf16 round-to-nearest-even (finite inputs only)
__device__ inline unsigned short f2bf(float f) {
    unsigned u = __builtin_bit_cast(unsigned, f);
    u = (u + 0x7fffu + ((u >> 16) & 1u)) >> 16;
    return (unsigned short)u;
}

__device__ inline short8 cvt8(f32x4 a, f32x4 b) {
    short8 r;
    r[0] = (short)f2bf(a.x); r[1] = (short)f2bf(a.y);
    r[2] = (short)f2bf(a.z); r[3] = (short)f2bf(a.w);
    r[4] = (short)f2bf(b.x); r[5] = (short)f2bf(b.y);
    r[6] = (short)f2bf(b.z); r[7] = (short)f2bf(b.w);
    return r;
}

// ---- k1 (full-ws): degree + bf16(A) emission  [R13 verbatim, PASSED] -------
__global__ __launch_bounds__(256) void k1_deg_cvt(const float* __restrict__ A,
                                                  float* __restrict__ dinv,
                                                  unsigned short* __restrict__ Abf) {
    __shared__ float red[256];
    int row = blockIdx.x;
    int t = threadIdx.x;
    const f32x4* ap = (const f32x4*)(A + (size_t)row * NN);
    f32x4 v0 = ap[2 * t];
    f32x4 v1 = ap[2 * t + 1];
    *(short8*)(Abf + (size_t)row * NN + t * 8) = cvt8(v0, v1);
    red[t] = v0.x + v0.y + v0.z + v0.w + v1.x + v1.y + v1.z + v1.w;
    __syncthreads();
    #pragma unroll
    for (int s = 128; s > 0; s >>= 1) {
        if (t < s) red[t] += red[t + s];
        __syncthreads();
    }
    if (t == 0) dinv[row] = rsqrtf(fmaxf(red[0], 1e-6f));
}

// ---- k1 (fallback): degree only  [R12 verbatim] ----------------------------
__global__ __launch_bounds__(256) void k1_deg(const float* __restrict__ A,
                                              float* __restrict__ dinv) {
    __shared__ float red[256];
    int row = blockIdx.x;
    int t = threadIdx.x;
    const f32x4* ap = (const f32x4*)(A + (size_t)row * NN);
    f32x4 v0 = ap[t];
    f32x4 v1 = ap[t + 256];
    red[t] = v0.x + v0.y + v0.z + v0.w + v1.x + v1.y + v1.z + v1.w;
    __syncthreads();
    #pragma unroll
    for (int s = 128; s > 0; s >>= 1) {
        if (t < s) red[t] += red[t + s];
        __syncthreads();
    }
    if (t == 0) dinv[row] = rsqrtf(fmaxf(red[0], 1e-6f));
}

// ---- k2: Zt[b][o][m] = bf16(dinv[b,m] * dot(X[b,m,:], W[o,:]))  [R12 verbatim]
__global__ __launch_bounds__(256) void k2_zt(const float* __restrict__ X,
                                             const float* __restrict__ W,
                                             const float* __restrict__ dinv,
                                             unsigned short* __restrict__ Zt) {
    __shared__ float Ws[FF * FF];           // 64 KB
    int blk = blockIdx.x;
    int b  = blk >> 6;                      // 0..3
    int mc = (blk >> 3) & 7;                // 0..7
    int oc = blk & 7;                       // 0..7
    int t  = threadIdx.x;
    int m  = mc * 256 + t;                  // 0..2047

    {
        f32x4* wd = (f32x4*)Ws;
        const f32x4* wsrc = (const f32x4*)W;
        #pragma unroll
        for (int j = 0; j < 16; ++j) wd[t + 256 * j] = wsrc[t + 256 * j];
    }
    __syncthreads();

    float acc[16];
    #pragma unroll
    for (int j = 0; j < 16; ++j) acc[j] = 0.f;

    const f32x4* xr = (const f32x4*)(X + ((size_t)b * NN + m) * FF);
    for (int f4 = 0; f4 < FF / 4; ++f4) {
        f32x4 xv = xr[f4];
        #pragma unroll
        for (int j = 0; j < 16; ++j) {
            f32x4 wv = *(const f32x4*)&Ws[(oc * 16 + j) * FF + f4 * 4];
            acc[j] += xv.x * wv.x + xv.y * wv.y + xv.z * wv.z + xv.w * wv.w;
        }
    }
    float dv = dinv[b * NN + m];
    #pragma unroll
    for (int j = 0; j < 16; ++j)
        Zt[((size_t)b * FF + oc * 16 + j) * NN + m] = f2bf(acc[j] * dv);
}

// ---- k3 (full-ws): wave-private, no barriers, no LDS -----------------------
// 512 blocks x 256 thr = 2048 waves; wave tile 16n x 32o. Per k-step: 3 clean
// short8 global loads + 2 MFMA; unroll 8 -> ~24 loads in flight per wave; no
// __syncthreads => no vmcnt(0) drains. A from Abf16 (single pass, L3-warm);
// Zt L2-resident (512 KB/batch). Fragments: A row=l15 k=kgrp+j; B col=l15
// same k; C/D col=l15 row=(lane>>4)*4+r  (R10..R14-verified conventions).
__global__ __launch_bounds__(256) void k3_wave(const unsigned short* __restrict__ Abf,
                                               const unsigned short* __restrict__ Zt,
                                               const float* __restrict__ dinv,
                                               const float* __restrict__ bias,
                                               float* __restrict__ out) {
    int blk = blockIdx.x;                   // 0..511
    int b   = blk >> 7;                     // 0..3
    int n0  = (blk & 127) * 16;             // 0..2032
    int t   = threadIdx.x;
    int w   = t >> 6, lane = t & 63;
    int l15 = lane & 15, kgrp = (lane >> 4) * 8;
    int o0  = w * 32;                       // wave owns o [o0, o0+32)

    const unsigned short* Ar = Abf + ((size_t)b * NN + n0 + l15) * NN + kgrp;
    const unsigned short* Z0 = Zt + ((size_t)b * FF + o0 + l15) * NN + kgrp;
    const unsigned short* Z1 = Z0 + (size_t)16 * NN;

    f32x4 acc0 = (f32x4){0.f, 0.f, 0.f, 0.f};
    f32x4 acc1 = (f32x4){0.f, 0.f, 0.f, 0.f};

    #pragma unroll 8
    for (int kk = 0; kk < NN; kk += 32) {
        short8 af  = *(const short8*)(Ar + kk);
        short8 bf0 = *(const short8*)(Z0 + kk);
        short8 bf1 = *(const short8*)(Z1 + kk);
        acc0 = __builtin_amdgcn_mfma_f32_16x16x32_bf16(af, bf0, acc0, 0, 0, 0);
        acc1 = __builtin_amdgcn_mfma_f32_16x16x32_bf16(af, bf1, acc1, 0, 0, 0);
    }

    int drow = (lane >> 4) * 4;
    float bv0 = bias[o0 + l15];
    float bv1 = bias[o0 + 16 + l15];
    #pragma unroll
    for (int r = 0; r < 4; ++r) {
        int n = n0 + drow + r;
        float dv = dinv[b * NN + n];
        float* orow = out + ((size_t)b * NN + n) * FF;
        orow[o0 + l15]      = dv * acc0[r] + bv0;
        orow[o0 + 16 + l15] = dv * acc1[r] + bv1;
    }
}

// ---- k3 (fallback): R12's LDS-staged depth-2 pipeline [verbatim] -----------
__global__ __launch_bounds__(256) void k3_mfma(const float* __restrict__ A,
                                               const unsigned short* __restrict__ Zt,
                                               const float* __restrict__ dinv,
                                               const float* __restrict__ bias,
                                               float* __restrict__ out) {
    __shared__ unsigned short As[2][16][72];
    __shared__ unsigned short Zs[2][128][72];
    int blk = blockIdx.x;
    int b   = blk >> 7;
    int n0  = (blk & 127) * 16;
    int t   = threadIdx.x;
    int w   = t >> 6, lane = t & 63;
    int l15 = lane & 15, kgrp = (lane >> 4) * 8;

    const float* Ab = A + (size_t)b * NN * NN;
    const unsigned short* Zb = Zt + (size_t)b * FF * NN;

    int ar = t >> 3;
    int ac = (t & 7) * 8;
    int zo = t >> 1;
    int zk = (t & 1) * 32;

    f32x4 acc[2];
    acc[0] = (f32x4){0.f, 0.f, 0.f, 0.f};
    acc[1] = (f32x4){0.f, 0.f, 0.f, 0.f};

    f32x4 pa0, pa1;  short8 pz0, pz1, pz2, pz3;
    f32x4 qa0, qa1;  short8 qz0, qz1, qz2, qz3;

    #define LOADT(A0, A1, Z0, Z1, Z2, Z3, k0)                                \
        do {                                                                 \
            if (t < 128) {                                                   \
                const float* asrc = Ab + (size_t)(n0 + ar) * NN + (k0) + ac; \
                A0 = *(const f32x4*)asrc;                                    \
                A1 = *(const f32x4*)(asrc + 4);                              \
            }                                                                \
            const unsigned short* zsrc = Zb + (size_t)zo * NN + (k0) + zk;   \
            Z0 = *(const short8*)(zsrc);                                     \
            Z1 = *(const short8*)(zsrc + 8);                                 \
            Z2 = *(const short8*)(zsrc + 16);                                \
            Z3 = *(const short8*)(zsrc + 24);                                \
        } while (0)

    #define WRITET(buf, A0, A1, Z0, Z1, Z2, Z3)                              \
        do {                                                                 \
            if (t < 128) *(short8*)&As[buf][ar][ac] = cvt8(A0, A1);          \
            *(short8*)&Zs[buf][zo][zk]      = Z0;                            \
            *(short8*)&Zs[buf][zo][zk + 8]  = Z1;                            \
            *(short8*)&Zs[buf][zo][zk + 16] = Z2;                            \
            *(short8*)&Zs[buf][zo][zk + 24] = Z3;                            \
        } while (0)

    #define MFMAS(cur)                                                       \
        do {                                                                 \
            _Pragma("unroll")                                                \
            for (int ks = 0; ks < 64; ks += 32) {                            \
                short8 af = *(const short8*)&As[cur][l15][ks + kgrp];        \
                short8 bf0 = *(const short8*)&Zs[cur][w * 32 + l15][ks + kgrp];       \
                short8 bf1 = *(const short8*)&Zs[cur][w * 32 + 16 + l15][ks + kgrp];  \
                acc[0] = __builtin_amdgcn_mfma_f32_16x16x32_bf16(af, bf0, acc[0], 0, 0, 0); \
                acc[1] = __builtin_amdgcn_mfma_f32_16x16x32_bf16(af, bf1, acc[1], 0, 0, 0); \
            }                                                                \
        } while (0)

    LOADT(pa0, pa1, pz0, pz1, pz2, pz3, 0);
    WRITET(0, pa0, pa1, pz0, pz1, pz2, pz3);
    LOADT(pa0, pa1, pz0, pz1, pz2, pz3, 64);
    __syncthreads();

    for (int it = 0; it < 32; it += 2) {
        if (it + 2 < 32) LOADT(qa0, qa1, qz0, qz1, qz2, qz3, (it + 2) * 64);
        MFMAS(0);
        if (it + 1 < 32) WRITET(1, pa0, pa1, pz0, pz1, pz2, pz3);
        __syncthreads();
        if (it + 1 < 32) {
            if (it + 3 < 32) LOADT(pa0, pa1, pz0, pz1, pz2, pz3, (it + 3) * 64);
            MFMAS(1);
            if (it + 2 < 32) WRITET(0, qa0, qa1, qz0, qz1, qz2, qz3);
            __syncthreads();
        }
    }

    int drow = (lane >> 4) * 4;
    #pragma unroll
    for (int tt = 0; tt < 2; ++tt) {
        int o = w * 32 + tt * 16 + l15;
        float bv = bias[o];
        #pragma unroll
        for (int r = 0; r < 4; ++r) {
            int n = n0 + drow + r;
            float dv = dinv[b * NN + n];
            out[((size_t)b * NN + n) * FF + o] = dv * acc[tt][r] + bv;
        }
    }
    #undef LOADT
    #undef WRITET
    #undef MFMAS
}

extern "C" void kernel_launch(void* const* d_in, const int* in_sizes, int n_in,
                              void* d_out, int out_size, void* d_ws, size_t ws_size,
                              hipStream_t stream) {
    // Bind inputs by element count (all distinct; order-proof):
    const float *X = nullptr, *A = nullptr, *W = nullptr, *bias = nullptr;
    for (int i = 0; i < n_in; ++i) {
        switch (in_sizes[i]) {
            case 16777216: A    = (const float*)d_in[i]; break;  // [4,2048,2048]
            case 1048576:  X    = (const float*)d_in[i]; break;  // [4,2048,128]
            case 16384:    W    = (const float*)d_in[i]; break;  // [128,128]
            case 128:      bias = (const float*)d_in[i]; break;  // [128]
            default: break;
        }
    }
    float* out = (float*)d_out;
    if (!X || !A || !W || !bias) return;        // signature: absmax 0.7578125
    if (out_size != 4 * NN * FF) return;
    if (ws_size < (size_t)WS_BASE) return;

    float* dinv        = (float*)d_ws;                            // 32 KB
    unsigned short* Zt = (unsigned short*)((char*)d_ws + 32768);  // 2 MB bf16

    if (ws_size >= (size_t)WS_FULL) {
        unsigned short* Abf = (unsigned short*)((char*)d_ws + WS_BASE);  // 33.5 MB
        k1_deg_cvt<<<4 * NN, 256, 0, stream>>>(A, dinv, Abf);
        k2_zt<<<256, 256, 0, stream>>>(X, W, dinv, Zt);
        k3_wave<<<512, 256, 0, stream>>>(Abf, Zt, dinv, bias, out);
    } else {
        k1_deg<<<4 * NN, 256, 0, stream>>>(A, dinv);
        k2_zt<<<256, 256, 0, stream>>>(X, W, dinv, Zt);
        k3_mfma<<<512, 256, 0, stream>>>(A, Zt, dinv, bias, out);
    }
}

// Round 17
// 52.229 us; speedup vs baseline: 1.4816x; 1.4816x over previous
//
#include <hip/hip_runtime.h>

// GraphConv: out = d ∘ (A @ ((d∘X) @ W^T)) + b,  d = rsqrt(clip(rowsum(A),1e-6))
// B=4, N=2048, F=128. All f32 I/O, size-based binding (R6-verified).
// Best = R12 (52.2 µs). Diagnosis: k3's __syncthreads lowers to
// s_waitcnt vmcnt(0) lgkmcnt(0) + s_barrier -> drains the depth-2 prefetch
// at every barrier (m97 structural stall). R16 = R12 with ONLY the barrier
// discipline changed (T4-lite): lgkmcnt(0) + raw s_barrier, vmcnt left
// counted (compiler's dependency waits). Everything else byte-identical.

#define NN 2048
#define FF 128
#define WS_NEED (32768u + 4u * 128u * 2048u * 2u)   // dinv(32KB)+Zt(2MB)

typedef __attribute__((ext_vector_type(4))) float f32x4;
typedef __attribute__((ext_vector_type(8))) short short8;

// f32 -> bf16 round-to-nearest-even (finite inputs only)
__device__ inline unsigned short f2bf(float f) {
    unsigned u = __builtin_bit_cast(unsigned, f);
    u = (u + 0x7fffu + ((u >> 16) & 1u)) >> 16;
    return (unsigned short)u;
}

__device__ inline short8 cvt8(f32x4 a, f32x4 b) {
    short8 r;
    r[0] = (short)f2bf(a.x); r[1] = (short)f2bf(a.y);
    r[2] = (short)f2bf(a.z); r[3] = (short)f2bf(a.w);
    r[4] = (short)f2bf(b.x); r[5] = (short)f2bf(b.y);
    r[6] = (short)f2bf(b.z); r[7] = (short)f2bf(b.w);
    return r;
}

// Barrier that does NOT drain vmcnt: publish LDS writes (lgkmcnt only),
// raw s_barrier, compiler memory fences on both sides.
#define SOFT_BARRIER()                                           \
    do {                                                         \
        asm volatile("s_waitcnt lgkmcnt(0)" ::: "memory");       \
        __builtin_amdgcn_s_barrier();                            \
        asm volatile("" ::: "memory");                           \
    } while (0)

// ---- k1: dinv[row] = rsqrt(max(rowsum(A),1e-6))  [R12 verbatim] ------------
__global__ __launch_bounds__(256) void k1_deg(const float* __restrict__ A,
                                              float* __restrict__ dinv) {
    __shared__ float red[256];
    int row = blockIdx.x;
    int t = threadIdx.x;
    const f32x4* ap = (const f32x4*)(A + (size_t)row * NN);
    f32x4 v0 = ap[t];
    f32x4 v1 = ap[t + 256];
    red[t] = v0.x + v0.y + v0.z + v0.w + v1.x + v1.y + v1.z + v1.w;
    __syncthreads();
    #pragma unroll
    for (int s = 128; s > 0; s >>= 1) {
        if (t < s) red[t] += red[t + s];
        __syncthreads();
    }
    if (t == 0) dinv[row] = rsqrtf(fmaxf(red[0], 1e-6f));
}

// ---- k2: Zt[b][o][m] = bf16(dinv[b,m] * dot(X[b,m,:], W[o,:]))  [R12 verbatim]
__global__ __launch_bounds__(256) void k2_zt(const float* __restrict__ X,
                                             const float* __restrict__ W,
                                             const float* __restrict__ dinv,
                                             unsigned short* __restrict__ Zt) {
    __shared__ float Ws[FF * FF];           // 64 KB
    int blk = blockIdx.x;
    int b  = blk >> 6;                      // 0..3
    int mc = (blk >> 3) & 7;                // 0..7
    int oc = blk & 7;                       // 0..7
    int t  = threadIdx.x;
    int m  = mc * 256 + t;                  // 0..2047

    {
        f32x4* wd = (f32x4*)Ws;
        const f32x4* wsrc = (const f32x4*)W;
        #pragma unroll
        for (int j = 0; j < 16; ++j) wd[t + 256 * j] = wsrc[t + 256 * j];
    }
    __syncthreads();

    float acc[16];
    #pragma unroll
    for (int j = 0; j < 16; ++j) acc[j] = 0.f;

    const f32x4* xr = (const f32x4*)(X + ((size_t)b * NN + m) * FF);
    for (int f4 = 0; f4 < FF / 4; ++f4) {
        f32x4 xv = xr[f4];
        #pragma unroll
        for (int j = 0; j < 16; ++j) {
            f32x4 wv = *(const f32x4*)&Ws[(oc * 16 + j) * FF + f4 * 4];
            acc[j] += xv.x * wv.x + xv.y * wv.y + xv.z * wv.z + xv.w * wv.w;
        }
    }
    float dv = dinv[b * NN + m];
    #pragma unroll
    for (int j = 0; j < 16; ++j)
        Zt[((size_t)b * FF + oc * 16 + j) * NN + m] = f2bf(acc[j] * dv);
}

// ---- k3: out[b,n,o] = dinv[b,n] * sum_m A[b,n,m]*Z[m,o] + bias[o] ----------
// R12's kernel verbatim EXCEPT __syncthreads -> SOFT_BARRIER (no vmcnt drain;
// depth-2 prefetch loads stay in flight across barriers).
__global__ __launch_bounds__(256) void k3_mfma(const float* __restrict__ A,
                                               const unsigned short* __restrict__ Zt,
                                               const float* __restrict__ dinv,
                                               const float* __restrict__ bias,
                                               float* __restrict__ out) {
    __shared__ unsigned short As[2][16][72];    // A tile  [n][k] bf16
    __shared__ unsigned short Zs[2][128][72];   // Z^T tile [o][k] bf16
    int blk = blockIdx.x;                   // 0..511
    int b   = blk >> 7;                     // 0..3
    int n0  = (blk & 127) * 16;             // 0..2032
    int t   = threadIdx.x;
    int w   = t >> 6, lane = t & 63;
    int l15 = lane & 15, kgrp = (lane >> 4) * 8;

    const float* Ab = A + (size_t)b * NN * NN;
    const unsigned short* Zb = Zt + (size_t)b * FF * NN;

    int ar = t >> 3;                        // (t<128): 0..15
    int ac = (t & 7) * 8;                   // 0..56
    int zo = t >> 1;                        // 0..127
    int zk = (t & 1) * 32;                  // 0 or 32

    f32x4 acc[2];
    acc[0] = (f32x4){0.f, 0.f, 0.f, 0.f};
    acc[1] = (f32x4){0.f, 0.f, 0.f, 0.f};

    f32x4 pa0, pa1;  short8 pz0, pz1, pz2, pz3;   // set P
    f32x4 qa0, qa1;  short8 qz0, qz1, qz2, qz3;   // set Q

    #define LOADT(A0, A1, Z0, Z1, Z2, Z3, k0)                                \
        do {                                                                 \
            if (t < 128) {                                                   \
                const float* asrc = Ab + (size_t)(n0 + ar) * NN + (k0) + ac; \
                A0 = *(const f32x4*)asrc;                                    \
                A1 = *(const f32x4*)(asrc + 4);                              \
            }                                                                \
            const unsigned short* zsrc = Zb + (size_t)zo * NN + (k0) + zk;   \
            Z0 = *(const short8*)(zsrc);                                     \
            Z1 = *(const short8*)(zsrc + 8);                                 \
            Z2 = *(const short8*)(zsrc + 16);                                \
            Z3 = *(const short8*)(zsrc + 24);                                \
        } while (0)

    #define WRITET(buf, A0, A1, Z0, Z1, Z2, Z3)                              \
        do {                                                                 \
            if (t < 128) *(short8*)&As[buf][ar][ac] = cvt8(A0, A1);          \
            *(short8*)&Zs[buf][zo][zk]      = Z0;                            \
            *(short8*)&Zs[buf][zo][zk + 8]  = Z1;                            \
            *(short8*)&Zs[buf][zo][zk + 16] = Z2;                            \
            *(short8*)&Zs[buf][zo][zk + 24] = Z3;                            \
        } while (0)

    #define MFMAS(cur)                                                       \
        do {                                                                 \
            _Pragma("unroll")                                                \
            for (int ks = 0; ks < 64; ks += 32) {                            \
                short8 af = *(const short8*)&As[cur][l15][ks + kgrp];        \
                short8 bf0 = *(const short8*)&Zs[cur][w * 32 + l15][ks + kgrp];       \
                short8 bf1 = *(const short8*)&Zs[cur][w * 32 + 16 + l15][ks + kgrp];  \
                acc[0] = __builtin_amdgcn_mfma_f32_16x16x32_bf16(af, bf0, acc[0], 0, 0, 0); \
                acc[1] = __builtin_amdgcn_mfma_f32_16x16x32_bf16(af, bf1, acc[1], 0, 0, 0); \
            }                                                                \
        } while (0)

    LOADT(pa0, pa1, pz0, pz1, pz2, pz3, 0);
    WRITET(0, pa0, pa1, pz0, pz1, pz2, pz3);
    LOADT(pa0, pa1, pz0, pz1, pz2, pz3, 64);
    SOFT_BARRIER();

    for (int it = 0; it < 32; it += 2) {
        if (it + 2 < 32) LOADT(qa0, qa1, qz0, qz1, qz2, qz3, (it + 2) * 64);
        MFMAS(0);
        if (it + 1 < 32) WRITET(1, pa0, pa1, pz0, pz1, pz2, pz3);
        SOFT_BARRIER();
        if (it + 1 < 32) {
            if (it + 3 < 32) LOADT(pa0, pa1, pz0, pz1, pz2, pz3, (it + 3) * 64);
            MFMAS(1);
            if (it + 2 < 32) WRITET(0, qa0, qa1, qz0, qz1, qz2, qz3);
            SOFT_BARRIER();
        }
    }

    int drow = (lane >> 4) * 4;
    #pragma unroll
    for (int tt = 0; tt < 2; ++tt) {
        int o = w * 32 + tt * 16 + l15;
        float bv = bias[o];
        #pragma unroll
        for (int r = 0; r < 4; ++r) {
            int n = n0 + drow + r;
            float dv = dinv[b * NN + n];
            out[((size_t)b * NN + n) * FF + o] = dv * acc[tt][r] + bv;
        }
    }
    #undef LOADT
    #undef WRITET
    #undef MFMAS
}

extern "C" void kernel_launch(void* const* d_in, const int* in_sizes, int n_in,
                              void* d_out, int out_size, void* d_ws, size_t ws_size,
                              hipStream_t stream) {
    // Bind inputs by element count (all distinct; order-proof):
    const float *X = nullptr, *A = nullptr, *W = nullptr, *bias = nullptr;
    for (int i = 0; i < n_in; ++i) {
        switch (in_sizes[i]) {
            case 16777216: A    = (const float*)d_in[i]; break;  // [4,2048,2048]
            case 1048576:  X    = (const float*)d_in[i]; break;  // [4,2048,128]
            case 16384:    W    = (const float*)d_in[i]; break;  // [128,128]
            case 128:      bias = (const float*)d_in[i]; break;  // [128]
            default: break;
        }
    }
    float* out = (float*)d_out;
    if (!X || !A || !W || !bias) return;        // signature: absmax 0.7578125
    if (out_size != 4 * NN * FF) return;
    if (ws_size < (size_t)WS_NEED) return;

    float* dinv        = (float*)d_ws;                            // 32 KB
    unsigned short* Zt = (unsigned short*)((char*)d_ws + 32768);  // 2 MB bf16

    k1_deg<<<4 * NN, 256, 0, stream>>>(A, dinv);
    k2_zt<<<256, 256, 0, stream>>>(X, W, dinv, Zt);
    k3_mfma<<<512, 256, 0, stream>>>(A, Zt, dinv, bias, out);
}